// Round 15
// baseline (1413.873 us; speedup 1.0000x reference)
//
#include <hip/hip_runtime.h>
#include <math.h>

namespace {

constexpr int Bb = 256, Tt = 512, Dp = 256, Hh = 128, G = 512;
constexpr int M = Tt * Bb; // 131072 rows (t-major: row = t*B + b)

typedef __attribute__((ext_vector_type(8))) short short8v;
typedef __attribute__((ext_vector_type(4))) float f32x4;

__device__ __forceinline__ float sigf(float x) {
  return __builtin_amdgcn_rcpf(1.0f + __expf(-x));
}
__device__ __forceinline__ float tanhfast(float x) {
  const float e = __expf(2.0f * x);
  return 1.0f - 2.0f * __builtin_amdgcn_rcpf(e + 1.0f);
}
__device__ __forceinline__ float b2f(unsigned short u) {
  return __uint_as_float((unsigned int)u << 16);
}
__device__ __forceinline__ unsigned short f2b(float f) {
  unsigned int u = __float_as_uint(f);
  u += 0x7FFFu + ((u >> 16) & 1u);   // round-to-nearest-even
  return (unsigned short)(u >> 16);
}
__device__ __forceinline__ unsigned int pack2(float a, float b) {
  return (unsigned int)f2b(a) | ((unsigned int)f2b(b) << 16);
}
// direct global->LDS DMA, 16B per lane (dest = wave-uniform base + lane*16)
__device__ __forceinline__ void gload16(const unsigned short* g, unsigned short* l) {
  __builtin_amdgcn_global_load_lds(
      (const __attribute__((address_space(1))) unsigned int*)g,
      (__attribute__((address_space(3))) unsigned int*)l, 16, 0, 0);
}
__device__ __forceinline__ void block_sync_lds() {
  __builtin_amdgcn_sched_barrier(0);
  asm volatile("s_waitcnt lgkmcnt(0)" ::: "memory");
  __builtin_amdgcn_s_barrier();
  __builtin_amdgcn_sched_barrier(0);
}

// fp32 -> bf16 flat convert (weights). n multiple of 1024.
__global__ __launch_bounds__(256) void wconv_k(const float* __restrict__ src,
                                               unsigned short* __restrict__ dst) {
  const int i = (blockIdx.x * 256 + threadIdx.x) * 4;
  const float4 v = *reinterpret_cast<const float4*>(src + i);
  uint2 o; o.x = pack2(v.x, v.y); o.y = pack2(v.z, v.w);
  *reinterpret_cast<uint2*>(dst + i) = o;
}

// x[B][T][128] fp32 -> xb[(t*256+b)][128] bf16
__global__ __launch_bounds__(256) void xconv_k(const float* __restrict__ x,
                                               unsigned short* __restrict__ out) {
  const int tid = threadIdx.x;
  const int m = blockIdx.x * 8 + (tid >> 5);
  const int t = m >> 8, b = m & 255;
  const int c4 = (tid & 31) * 4;
  const float4 v = *reinterpret_cast<const float4*>(x + ((size_t)b * Tt + t) * 128 + c4);
  uint2 o; o.x = pack2(v.x, v.y); o.y = pack2(v.z, v.w);
  *reinterpret_cast<uint2*>(out + (size_t)m * 128 + c4) = o;
}

// MFMA GEMM, all-bf16, global_load_lds staging (fragment-major chunks).
// 128x128 tile, 4 waves (64x64 each), BK=64 double-buffered.
// POT=1 (attention): tanh epilogue -> LDS tile -> MFMA vs Wa2 -> pot[M][8] f32.
template<int K, int POT, typename CT>
__global__ __launch_bounds__(256) void mgemm_k(const unsigned short* __restrict__ A,
    const unsigned short* __restrict__ W, const float* __restrict__ bias1,
    const float* __restrict__ bias2, const float* __restrict__ Wa2,
    CT* __restrict__ C, int N) {
  constexpr int NK = K / 64;
  __shared__ unsigned short smem[32768];   // aLds(2x8192) | wLds(2x8192); POT reuses as ptile
  unsigned short* aLds = smem;
  unsigned short* wLds = smem + 16384;
  const int tid = threadIdx.x;
  const int lane = tid & 63;
  const int wave = tid >> 6;
  const int wm = wave >> 1, wn = wave & 1;
  const int m0 = blockIdx.y * 128, n0 = blockIdx.x * 128;
  const int lrow = lane & 15, lk8 = (lane >> 4) * 8;

  const unsigned short* Ab = A + (size_t)(m0 + lrow) * K + lk8;
  const unsigned short* Wb = W + (size_t)(n0 + lrow) * K + lk8;

  auto stage = [&](int buf, int kb) {
#pragma unroll
    for (int i = 0; i < 4; ++i) {
      const int c = wave * 4 + i, f = c & 7, kc = c >> 3;
      const size_t go = (size_t)(f * 16) * K + kb * 64 + kc * 32;
      gload16(Ab + go, &aLds[buf * 8192 + c * 512]);
      gload16(Wb + go, &wLds[buf * 8192 + c * 512]);
    }
  };

  f32x4 acc[4][4] = {};
  stage(0, 0);
  __syncthreads();
  int cur = 0;
  for (int kb = 0; kb < NK; ++kb) {
    if (kb + 1 < NK) stage(cur ^ 1, kb + 1);   // issue next-tile DMA before compute
#pragma unroll
    for (int kc = 0; kc < 2; ++kc) {
      short8v af[4], bfr[4];
#pragma unroll
      for (int i = 0; i < 4; ++i)
        af[i] = *reinterpret_cast<const short8v*>(
            &aLds[cur * 8192 + ((kc * 8 + wm * 4 + i) * 64 + lane) * 8]);
#pragma unroll
      for (int j = 0; j < 4; ++j)
        bfr[j] = *reinterpret_cast<const short8v*>(
            &wLds[cur * 8192 + ((kc * 8 + wn * 4 + j) * 64 + lane) * 8]);
#pragma unroll
      for (int i = 0; i < 4; ++i)
#pragma unroll
        for (int j = 0; j < 4; ++j)
          acc[i][j] = __builtin_amdgcn_mfma_f32_16x16x32_bf16(af[i], bfr[j], acc[i][j], 0, 0, 0);
    }
    __syncthreads();   // drains staged DMA (vmcnt) + LDS reads; buffer swap safe
    cur ^= 1;
  }

  if constexpr (POT) {
    unsigned short* pt = smem;
#pragma unroll
    for (int j = 0; j < 4; ++j) {
      const int coln = wn * 64 + j * 16 + (lane & 15);
      const float bv = bias1[coln];
#pragma unroll
      for (int i = 0; i < 4; ++i) {
        const int rown = wm * 64 + i * 16 + ((lane >> 4) << 2);
#pragma unroll
        for (int r = 0; r < 4; ++r)
          pt[(rown + r) * 136 + coln] = f2b(tanhfast(acc[i][j][r] + bv));
      }
    }
    __syncthreads();
    short8v wfr[4];
#pragma unroll
    for (int ks = 0; ks < 4; ++ks) {
      short8v f = {0, 0, 0, 0, 0, 0, 0, 0};
      if (lrow < 8) {
        const float* src = Wa2 + lrow * 128 + ks * 32 + lk8;
        const float4 a = *reinterpret_cast<const float4*>(src);
        const float4 b = *reinterpret_cast<const float4*>(src + 4);
        f[0] = (short)f2b(a.x); f[1] = (short)f2b(a.y);
        f[2] = (short)f2b(a.z); f[3] = (short)f2b(a.w);
        f[4] = (short)f2b(b.x); f[5] = (short)f2b(b.y);
        f[6] = (short)f2b(b.z); f[7] = (short)f2b(b.w);
      }
      wfr[ks] = f;
    }
    float* pot = reinterpret_cast<float*>(C);
#pragma unroll
    for (int ff = 0; ff < 2; ++ff) {
      const int fr = wave * 2 + ff;
      f32x4 pacc = {0.f, 0.f, 0.f, 0.f};
#pragma unroll
      for (int ks = 0; ks < 4; ++ks) {
        const short8v af = *reinterpret_cast<const short8v*>(
            &pt[(fr * 16 + lrow) * 136 + ks * 32 + lk8]);
        pacc = __builtin_amdgcn_mfma_f32_16x16x32_bf16(af, wfr[ks], pacc, 0, 0, 0);
      }
      if ((lane & 15) < 8) {
#pragma unroll
        for (int r = 0; r < 4; ++r)
          pot[(size_t)(m0 + fr * 16 + ((lane >> 4) << 2) + r) * 8 + (lane & 15)] = pacc[r];
      }
    }
  } else {
#pragma unroll
    for (int j = 0; j < 4; ++j) {
      const int gn = n0 + wn * 64 + j * 16 + (lane & 15);
      float bv = bias1[gn];
      if (bias2) bv += bias2[gn];
#pragma unroll
      for (int i = 0; i < 4; ++i) {
        const int gmb = m0 + wm * 64 + i * 16 + ((lane >> 4) << 2);
#pragma unroll
        for (int r = 0; r < 4; ++r) {
          const float v = acc[i][j][r] + bv;
          const size_t oidx = (size_t)(gmb + r) * N + gn;
          if constexpr (sizeof(CT) == 2) C[oidx] = f2b(v); else C[oidx] = v;
        }
      }
    }
  }
}

// Dual-chain MFMA LSTM: 128 blocks (one batch PAIR each), 512 threads.
// Chain A = forward dir, chain B = backward dir, phase-shifted by half step:
//   half1: MFMA_A(s) || EW_B(s-1)   half2: MFMA_B(s) || EW_A(s)
// EW VALU overlaps the other chain's ds_read+MFMA latency in-wave.
// Rows at A-rows 0,4 (gates in reg0, owner lanes 0-31). hbuf single-buffered
// (read/write in different barrier intervals). Shared bfrag (same weights).
__global__ __launch_bounds__(512, 1) void lstm_k(const unsigned short* __restrict__ P,
    const float* __restrict__ Whh, const float* __restrict__ wtime,
    unsigned short* __restrict__ Y) {
  const int tid = threadIdx.x;
  const int lane = tid & 63;
  const int w = tid >> 6;        // wave 0..7
  const int u = lane & 15;
  const int q = lane >> 4;
  const int b0 = blockIdx.x * 2;

  __shared__ unsigned short hbufA[2048], hbufB[2048];  // [koct16][row16][8]; rows 0,4 live
  __shared__ unsigned int pgA[2][512], pgB[2][512];    // [par][row*256+word]
  __shared__ unsigned short histA[4096], histB[4096];  // [slot16][row2][col128]
  __shared__ float wts[32];

  // B fragments (shared by both chains): col = gt*128 + w*16 + u, k = ks*32+q*8+j
  short8v bfrag[4][4];
#pragma unroll
  for (int gt = 0; gt < 4; ++gt) {
    const int col = gt * 128 + w * 16 + u;
#pragma unroll
    for (int ks = 0; ks < 4; ++ks) {
      const int k0 = ks * 32 + q * 8;
      const float4 w0 = *reinterpret_cast<const float4*>(Whh + (size_t)col * 128 + k0);
      const float4 w1 = *reinterpret_cast<const float4*>(Whh + (size_t)col * 128 + k0 + 4);
      short8v f;
      f[0] = (short)f2b(w0.x); f[1] = (short)f2b(w0.y);
      f[2] = (short)f2b(w0.z); f[3] = (short)f2b(w0.w);
      f[4] = (short)f2b(w1.x); f[5] = (short)f2b(w1.y);
      f[6] = (short)f2b(w1.z); f[7] = (short)f2b(w1.w);
      bfrag[gt][ks] = f;
    }
  }

  for (int i = tid; i < 2048; i += 512) { hbufA[i] = 0; hbufB[i] = 0; }
  if (tid < 32) wts[tid] = wtime[tid];
  const unsigned int* P32 = reinterpret_cast<const unsigned int*>(P);
  const size_t bstep = (size_t)Bb * 256;
  const size_t word = (size_t)(b0 + (tid >> 8)) * 256 + (tid & 255);
  // A = fwd (t: 0..511), B = bwd (t: 511..0)
  pgA[0][tid] = P32[word];                              // A val step0
  unsigned int hA1 = P32[bstep + word];                 // val1
  unsigned int hA2 = P32[2 * bstep + word];             // val2
  pgB[1][tid] = P32[(size_t)(Tt - 1) * bstep + word];   // B val step0
  unsigned int hB1 = P32[(size_t)(Tt - 2) * bstep + word];
  unsigned int hB2 = P32[(size_t)(Tt - 3) * bstep + word];
  size_t poffA = 3 * bstep + word;
  size_t poffB = (size_t)(Tt - 4) * bstep + word;

  const int r_own = q & 1;           // owner lanes 0-31
  const int colh = w * 16 + u;
  float cA = 0.f, haA = 0.f, caA = 0.f;
  float cB = 0.f, haB = 0.f, caB = 0.f;
  f32x4 gB[4];                       // B gates persist half2(s) -> half1(s+1)
  __syncthreads();

  auto body = [&](int s, int par) {
    // ================= half 1: MFMA_A(s) || EW_B(s-1) =================
    unsigned int nA = 0;
    if (s + 3 < Tt) nA = P32[poffA];
    short8v af[4];
#pragma unroll
    for (int ks = 0; ks < 4; ++ks)
      af[ks] = *reinterpret_cast<const short8v*>(&hbufA[(ks * 4 + q) * 128 + u * 8]);
    f32x4 gA[4];
#pragma unroll
    for (int gt = 0; gt < 4; ++gt) {
      f32x4 acc = {0.f, 0.f, 0.f, 0.f};
#pragma unroll
      for (int ks = 0; ks < 4; ++ks)
        acc = __builtin_amdgcn_mfma_f32_16x16x32_bf16(af[ks], bfrag[gt][ks], acc, 0, 0, 0);
      gA[gt] = acc;
    }
    if (s < Tt - 1) pgA[par ^ 1][tid] = hA1;   // A val s+1
    if (s > 0 && lane < 32) {                  // EW_B(s-1): gates in gB (regs)
      const int sb = s - 1;
      const float wt = wts[sb & 31];
      float g4[4];
#pragma unroll
      for (int gt = 0; gt < 4; ++gt) {
        const unsigned int pw = pgB[par][r_own * 256 + gt * 64 + (colh >> 1)];
        const unsigned short pb = (colh & 1) ? (unsigned short)(pw >> 16)
                                             : (unsigned short)(pw & 0xFFFF);
        g4[gt] = gB[gt][0] + b2f(pb);
      }
      float cs = sigf(g4[1]) * cB + sigf(g4[0]) * tanhfast(g4[2]);
      float hn = sigf(g4[3]) * tanhfast(cs);
      haB += wt * hn; caB += wt * cs;
      if ((sb & 31) == 31) { hn = haB; cs = caB; haB = 0.f; caB = 0.f; }
      cB = cs;
      const unsigned short hb = f2b(hn);
      hbufB[(colh >> 3) * 128 + r_own * 32 + (colh & 7)] = hb;
      histB[((sb & 15) * 2 + r_own) * 128 + colh] = hb;
    }
    if ((s & 7) == 0 && s) {   // flush A steps s-8..s-1 (written thru half2(s-1))
      const int k = tid >> 6, r2 = (tid >> 5) & 1, c4 = (tid & 31) * 4;
      const int bs = s - 8;
      const uint2 v = *reinterpret_cast<const uint2*>(
          &histA[(((bs + k) & 15) * 2 + r2) * 128 + c4]);
      *reinterpret_cast<uint2*>(
          &Y[((size_t)(bs + k) * Bb + b0 + r2) * Dp + c4]) = v;
    }
    block_sync_lds();
    hA1 = hA2; hA2 = nA; poffA += bstep;

    // ================= half 2: MFMA_B(s) || EW_A(s) =================
    unsigned int nB = 0;
    if (s + 3 < Tt) nB = P32[poffB];
#pragma unroll
    for (int ks = 0; ks < 4; ++ks)
      af[ks] = *reinterpret_cast<const short8v*>(&hbufB[(ks * 4 + q) * 128 + u * 8]);
#pragma unroll
    for (int gt = 0; gt < 4; ++gt) {
      f32x4 acc = {0.f, 0.f, 0.f, 0.f};
#pragma unroll
      for (int ks = 0; ks < 4; ++ks)
        acc = __builtin_amdgcn_mfma_f32_16x16x32_bf16(af[ks], bfrag[gt][ks], acc, 0, 0, 0);
      gB[gt] = acc;
    }
    if (s < Tt - 1) pgB[par][tid] = hB1;   // B val s+1
    if (lane < 32) {                       // EW_A(s): gates in gA (regs)
      const float wt = wts[s & 31];
      float g4[4];
#pragma unroll
      for (int gt = 0; gt < 4; ++gt) {
        const unsigned int pw = pgA[par][r_own * 256 + gt * 64 + (colh >> 1)];
        const unsigned short pb = (colh & 1) ? (unsigned short)(pw >> 16)
                                             : (unsigned short)(pw & 0xFFFF);
        g4[gt] = gA[gt][0] + b2f(pb);
      }
      float cs = sigf(g4[1]) * cA + sigf(g4[0]) * tanhfast(g4[2]);
      float hn = sigf(g4[3]) * tanhfast(cs);
      haA += wt * hn; caA += wt * cs;
      if ((s & 31) == 31) { hn = haA; cs = caA; haA = 0.f; caA = 0.f; }
      cA = cs;
      const unsigned short hb = f2b(hn);
      hbufA[(colh >> 3) * 128 + r_own * 32 + (colh & 7)] = hb;
      histA[((s & 15) * 2 + r_own) * 128 + colh] = hb;
    }
    if ((s & 7) == 0 && s) {   // flush B steps s-8..s-1 (B step s-1 done half1(s))
      const int k = tid >> 6, r2 = (tid >> 5) & 1, c4 = (tid & 31) * 4;
      const int bs = s - 8;
      const uint2 v = *reinterpret_cast<const uint2*>(
          &histB[(((bs + k) & 15) * 2 + r2) * 128 + c4]);
      *reinterpret_cast<uint2*>(
          &Y[((size_t)(bs + k) * Bb + b0 + r2) * Dp + Hh + c4]) = v;
    }
    block_sync_lds();
    hB1 = hB2; hB2 = nB; poffB -= bstep;
  };

  for (int s = 0; s < Tt; s += 2) {
    body(s, 0);       // par literal 0
    body(s + 1, 1);   // par literal 1
  }
  // epilogue: finish B step 511 (gates in gB; pre-gates in pgB[0], see parity)
  if (lane < 32) {
    const int sb = Tt - 1;
    const float wt = wts[sb & 31];
    float g4[4];
#pragma unroll
    for (int gt = 0; gt < 4; ++gt) {
      const unsigned int pw = pgB[0][r_own * 256 + gt * 64 + (colh >> 1)];
      const unsigned short pb = (colh & 1) ? (unsigned short)(pw >> 16)
                                           : (unsigned short)(pw & 0xFFFF);
      g4[gt] = gB[gt][0] + b2f(pb);
    }
    float cs = sigf(g4[1]) * cB + sigf(g4[0]) * tanhfast(g4[2]);
    float hn = sigf(g4[3]) * tanhfast(cs);
    haB += wt * hn;
    if ((sb & 31) == 31) hn = haB;
    const unsigned short hb = f2b(hn);
    histB[((sb & 15) * 2 + r_own) * 128 + colh] = hb;
  }
  __syncthreads();
  {  // final flushes: steps 504..511 both chains
    const int k = tid >> 6, r2 = (tid >> 5) & 1, c4 = (tid & 31) * 4;
    const int bs = Tt - 8;
    const uint2 va = *reinterpret_cast<const uint2*>(
        &histA[(((bs + k) & 15) * 2 + r2) * 128 + c4]);
    *reinterpret_cast<uint2*>(
        &Y[((size_t)(bs + k) * Bb + b0 + r2) * Dp + c4]) = va;
    const uint2 vb = *reinterpret_cast<const uint2*>(
        &histB[(((bs + k) & 15) * 2 + r2) * 128 + c4]);
    *reinterpret_cast<uint2*>(
        &Y[((size_t)(bs + k) * Bb + b0 + r2) * Dp + Hh + c4]) = vb;
  }
}

// masked softmax over t for one (b,r); writes Wt[b][r][t]
__global__ __launch_bounds__(256) void softmax_k(const float* __restrict__ pot,
    const int* __restrict__ length, float* __restrict__ Wt) {
  const int b = blockIdx.x >> 3, r = blockIdx.x & 7;
  const int tid = threadIdx.x;
  const int len = length[b];
  __shared__ float rbuf[4];
  const int t1 = tid, t2 = tid + 256;
  const float x1 = (t1 < len) ? pot[((size_t)t1 * Bb + b) * 8 + r] : -INFINITY;
  const float x2 = (t2 < len) ? pot[((size_t)t2 * Bb + b) * 8 + r] : -INFINITY;
  float m = fmaxf(x1, x2);
#pragma unroll
  for (int off = 32; off >= 1; off >>= 1) m = fmaxf(m, __shfl_xor(m, off));
  if ((tid & 63) == 0) rbuf[tid >> 6] = m;
  __syncthreads();
  m = fmaxf(fmaxf(rbuf[0], rbuf[1]), fmaxf(rbuf[2], rbuf[3]));
  const float e1 = (t1 < len) ? __expf(x1 - m) : 0.f;
  const float e2 = (t2 < len) ? __expf(x2 - m) : 0.f;
  float ssum = e1 + e2;
#pragma unroll
  for (int off = 32; off >= 1; off >>= 1) ssum += __shfl_xor(ssum, off);
  __syncthreads();
  if ((tid & 63) == 0) rbuf[tid >> 6] = ssum;
  __syncthreads();
  ssum = rbuf[0] + rbuf[1] + rbuf[2] + rbuf[3];
  const float inv = 1.0f / ssum;
  float* wrow = Wt + ((size_t)b * 8 + r) * Tt;
  wrow[t1] = e1 * inv;
  wrow[t2] = e2 * inv;
}

// Per-b: pooled = sum_t w[r][t]*Y[t][b][:], logits, log_softmax, gram penalty.
__global__ __launch_bounds__(256) void pool_k(const unsigned short* __restrict__ Y,
    const float* __restrict__ Wt, const float* __restrict__ Wout,
    const float* __restrict__ bout, float* __restrict__ outF,
    float* __restrict__ penpart) {
  const int b = blockIdx.x;
  const int tid = threadIdx.x;
  __shared__ float ws[8 * 513];
  __shared__ float pooled[2048];
  __shared__ float red[256];
  __shared__ float lg[8];
  for (int i = tid; i < 4096; i += 256) ws[(i >> 9) * 513 + (i & 511)] = Wt[(size_t)b * 4096 + i];
  __syncthreads();
  float acc[8] = {};
  for (int t = 0; t < Tt; ++t) {
    const float y = b2f(Y[((size_t)t * Bb + b) * Dp + tid]);
#pragma unroll
    for (int r = 0; r < 8; ++r) acc[r] += ws[r * 513 + t] * y;
  }
#pragma unroll
  for (int r = 0; r < 8; ++r) pooled[r * 256 + tid] = acc[r];
  __syncthreads();
  for (int o = 0; o < 7; ++o) {
    float p = 0.f;
    for (int j = tid; j < 2048; j += 256) p += pooled[j] * Wout[(size_t)o * 2048 + j];
    red[tid] = p;
    __syncthreads();
    for (int st = 128; st >= 1; st >>= 1) {
      if (tid < st) red[tid] += red[tid + st];
      __syncthreads();
    }
    if (tid == 0) lg[o] = red[0] + bout[o];
    __syncthreads();
  }
  if (tid == 0) {
    float mx = lg[0];
    for (int o = 1; o < 7; ++o) mx = fmaxf(mx, lg[o]);
    float ssum = 0.f;
    for (int o = 0; o < 7; ++o) ssum += __expf(lg[o] - mx);
    const float lse = mx + __logf(ssum);
    for (int o = 0; o < 7; ++o) outF[b * 7 + o] = lg[o] - lse;
  }
  for (int i = tid; i < 4096; i += 256) {
    const int rr = i >> 9, t = i & 511;
    ws[rr * 513 + t] = sqrtf(ws[rr * 513 + t]);
  }
  __syncthreads();
  float pp = 0.f;
  if (tid < 64) {
    const int rr = tid >> 3, ssi = tid & 7;
    float g = 0.f;
    for (int t = 0; t < Tt; ++t) g += ws[rr * 513 + t] * ws[ssi * 513 + t];
    const float d = g - 1.0f;
    pp = d * d;
  }
  red[tid] = pp;
  __syncthreads();
  for (int st = 128; st >= 1; st >>= 1) {
    if (tid < st) red[tid] += red[tid + st];
    __syncthreads();
  }
  if (tid == 0) penpart[b] = red[0];
}

__global__ __launch_bounds__(256) void penred_k(const float* __restrict__ penpart,
                                                float* __restrict__ outp) {
  const int tid = threadIdx.x;
  __shared__ float red[256];
  red[tid] = penpart[tid];
  __syncthreads();
  for (int st = 128; st >= 1; st >>= 1) {
    if (tid < st) red[tid] += red[tid + st];
    __syncthreads();
  }
  if (tid == 0) outp[0] = red[0];
}

} // namespace

extern "C" void kernel_launch(void* const* d_in, const int* in_sizes, int n_in,
                              void* d_out, int out_size, void* d_ws, size_t ws_size,
                              hipStream_t stream) {
  (void)in_sizes; (void)n_in; (void)out_size;
  const float* x     = (const float*)d_in[0];
  const float* W_in  = (const float*)d_in[1];
  const float* b_in  = (const float*)d_in[2];
  const float* W_ih  = (const float*)d_in[3];
  const float* b_ih  = (const float*)d_in[4];
  const float* W_hh  = (const float*)d_in[5];
  const float* b_hh  = (const float*)d_in[6];
  const float* wtime = (const float*)d_in[7];
  const float* W_a1  = (const float*)d_in[8];
  const float* b_a1  = (const float*)d_in[9];
  const float* W_a2  = (const float*)d_in[10];
  const float* W_out = (const float*)d_in[11];
  const float* b_out = (const float*)d_in[12];
  const int*   length= (const int*)d_in[13];
  float* outF = (float*)d_out;

  typedef unsigned short bf16;
  char* ws = (char*)d_ws;
  size_t off = 0;
  auto alloc = [&](size_t bytes) {
    void* p = ws + off; off += (bytes + 255) & ~(size_t)255; return p;
  };
  bf16*  act  = (bf16*)alloc((size_t)M * 256 * 2);   // activations [T*B][256]
  bf16*  Pg   = (bf16*)alloc((size_t)M * 512 * 2);   // pre-gates  [T*B][512]
  bf16*  xb   = (bf16*)alloc((size_t)M * 128 * 2);   // x transposed+bf16
  float* pot  = (float*)alloc((size_t)M * 8 * 4);
  float* Wt   = (float*)alloc((size_t)Bb * 8 * Tt * 4);
  float* penp = (float*)alloc(Bb * 4);
  bf16*  Wihb = (bf16*)alloc(512 * 256 * 2);
  bf16*  Winb = (bf16*)alloc(256 * 128 * 2);
  bf16*  Wa1b = (bf16*)alloc(128 * 256 * 2);

  if (ws_size < off) return;  // workspace too small: clean absmax-fail, not a crash

  const dim3 blk(256);
  // pre-conversions (bit-identical to the stage-time conversions they replace)
  wconv_k<<<dim3(32),  blk, 0, stream>>>(W_in, Winb);
  wconv_k<<<dim3(128), blk, 0, stream>>>(W_ih, Wihb);
  wconv_k<<<dim3(32),  blk, 0, stream>>>(W_a1, Wa1b);
  xconv_k<<<dim3(M / 8), blk, 0, stream>>>(x, xb);
  // input layer
  mgemm_k<128, 0, bf16><<<dim3(2, M / 128), blk, 0, stream>>>(xb, Winb, b_in, nullptr, nullptr, act, 256);
  // layer 0
  mgemm_k<256, 0, bf16><<<dim3(4, M / 128), blk, 0, stream>>>(act, Wihb, b_ih, b_hh, nullptr, Pg, 512);
  lstm_k<<<dim3(128), dim3(512), 0, stream>>>(Pg, W_hh, wtime, act);
  // layer 1 (shared weights)
  mgemm_k<256, 0, bf16><<<dim3(4, M / 128), blk, 0, stream>>>(act, Wihb, b_ih, b_hh, nullptr, Pg, 512);
  lstm_k<<<dim3(128), dim3(512), 0, stream>>>(Pg, W_hh, wtime, act);
  // attention: tanh GEMM fused with pot projection
  mgemm_k<256, 1, float><<<dim3(1, M / 128), blk, 0, stream>>>(act, Wa1b, b_a1, nullptr, W_a2, pot, 128);
  softmax_k<<<dim3(Bb * 8), blk, 0, stream>>>(pot, length, Wt);
  pool_k<<<dim3(Bb), blk, 0, stream>>>(act, Wt, W_out, b_out, outF, penp);
  penred_k<<<dim3(1), blk, 0, stream>>>(penp, outF + Bb * 7);
}

// Round 16
// 899.138 us; speedup vs baseline: 1.5725x; 1.5725x over previous
//
#include <hip/hip_runtime.h>
#include <math.h>

namespace {

constexpr int Bb = 256, Tt = 512, Dp = 256, Hh = 128, G = 512;
constexpr int M = Tt * Bb; // 131072 rows (t-major: row = t*B + b)

typedef __attribute__((ext_vector_type(8))) short short8v;
typedef __attribute__((ext_vector_type(4))) float f32x4;

__device__ __forceinline__ float sigf(float x) {
  return __builtin_amdgcn_rcpf(1.0f + __expf(-x));
}
__device__ __forceinline__ float tanhfast(float x) {
  const float e = __expf(2.0f * x);
  return 1.0f - 2.0f * __builtin_amdgcn_rcpf(e + 1.0f);
}
__device__ __forceinline__ float b2f(unsigned short u) {
  return __uint_as_float((unsigned int)u << 16);
}
__device__ __forceinline__ unsigned short f2b(float f) {
  unsigned int u = __float_as_uint(f);
  u += 0x7FFFu + ((u >> 16) & 1u);   // round-to-nearest-even
  return (unsigned short)(u >> 16);
}
__device__ __forceinline__ unsigned int pack2(float a, float b) {
  return (unsigned int)f2b(a) | ((unsigned int)f2b(b) << 16);
}
// direct global->LDS DMA, 16B per lane (dest = wave-uniform base + lane*16)
__device__ __forceinline__ void gload16(const unsigned short* g, unsigned short* l) {
  __builtin_amdgcn_global_load_lds(
      (const __attribute__((address_space(1))) unsigned int*)g,
      (__attribute__((address_space(3))) unsigned int*)l, 16, 0, 0);
}
__device__ __forceinline__ void block_sync_lds() {
  __builtin_amdgcn_sched_barrier(0);
  asm volatile("s_waitcnt lgkmcnt(0)" ::: "memory");
  __builtin_amdgcn_s_barrier();
  __builtin_amdgcn_sched_barrier(0);
}

// fp32 -> bf16 flat convert (weights). n multiple of 1024.
__global__ __launch_bounds__(256) void wconv_k(const float* __restrict__ src,
                                               unsigned short* __restrict__ dst) {
  const int i = (blockIdx.x * 256 + threadIdx.x) * 4;
  const float4 v = *reinterpret_cast<const float4*>(src + i);
  uint2 o; o.x = pack2(v.x, v.y); o.y = pack2(v.z, v.w);
  *reinterpret_cast<uint2*>(dst + i) = o;
}

// x[B][T][128] fp32 -> xb[(t*256+b)][128] bf16
__global__ __launch_bounds__(256) void xconv_k(const float* __restrict__ x,
                                               unsigned short* __restrict__ out) {
  const int tid = threadIdx.x;
  const int m = blockIdx.x * 8 + (tid >> 5);
  const int t = m >> 8, b = m & 255;
  const int c4 = (tid & 31) * 4;
  const float4 v = *reinterpret_cast<const float4*>(x + ((size_t)b * Tt + t) * 128 + c4);
  uint2 o; o.x = pack2(v.x, v.y); o.y = pack2(v.z, v.w);
  *reinterpret_cast<uint2*>(out + (size_t)m * 128 + c4) = o;
}

// MFMA GEMM, all-bf16, global_load_lds staging (fragment-major chunks).
// 128x128 tile, 4 waves (64x64 each), BK=64 double-buffered.
// POT=1 (attention): tanh epilogue -> LDS tile -> MFMA vs Wa2 -> pot[M][8] f32.
template<int K, int POT, typename CT>
__global__ __launch_bounds__(256) void mgemm_k(const unsigned short* __restrict__ A,
    const unsigned short* __restrict__ W, const float* __restrict__ bias1,
    const float* __restrict__ bias2, const float* __restrict__ Wa2,
    CT* __restrict__ C, int N) {
  constexpr int NK = K / 64;
  __shared__ unsigned short smem[32768];   // aLds(2x8192) | wLds(2x8192); POT reuses as ptile
  unsigned short* aLds = smem;
  unsigned short* wLds = smem + 16384;
  const int tid = threadIdx.x;
  const int lane = tid & 63;
  const int wave = tid >> 6;
  const int wm = wave >> 1, wn = wave & 1;
  const int m0 = blockIdx.y * 128, n0 = blockIdx.x * 128;
  const int lrow = lane & 15, lk8 = (lane >> 4) * 8;

  const unsigned short* Ab = A + (size_t)(m0 + lrow) * K + lk8;
  const unsigned short* Wb = W + (size_t)(n0 + lrow) * K + lk8;

  auto stage = [&](int buf, int kb) {
#pragma unroll
    for (int i = 0; i < 4; ++i) {
      const int c = wave * 4 + i, f = c & 7, kc = c >> 3;
      const size_t go = (size_t)(f * 16) * K + kb * 64 + kc * 32;
      gload16(Ab + go, &aLds[buf * 8192 + c * 512]);
      gload16(Wb + go, &wLds[buf * 8192 + c * 512]);
    }
  };

  f32x4 acc[4][4] = {};
  stage(0, 0);
  __syncthreads();
  int cur = 0;
  for (int kb = 0; kb < NK; ++kb) {
    if (kb + 1 < NK) stage(cur ^ 1, kb + 1);   // issue next-tile DMA before compute
#pragma unroll
    for (int kc = 0; kc < 2; ++kc) {
      short8v af[4], bfr[4];
#pragma unroll
      for (int i = 0; i < 4; ++i)
        af[i] = *reinterpret_cast<const short8v*>(
            &aLds[cur * 8192 + ((kc * 8 + wm * 4 + i) * 64 + lane) * 8]);
#pragma unroll
      for (int j = 0; j < 4; ++j)
        bfr[j] = *reinterpret_cast<const short8v*>(
            &wLds[cur * 8192 + ((kc * 8 + wn * 4 + j) * 64 + lane) * 8]);
#pragma unroll
      for (int i = 0; i < 4; ++i)
#pragma unroll
        for (int j = 0; j < 4; ++j)
          acc[i][j] = __builtin_amdgcn_mfma_f32_16x16x32_bf16(af[i], bfr[j], acc[i][j], 0, 0, 0);
    }
    __syncthreads();   // drains staged DMA (vmcnt) + LDS reads; buffer swap safe
    cur ^= 1;
  }

  if constexpr (POT) {
    unsigned short* pt = smem;
#pragma unroll
    for (int j = 0; j < 4; ++j) {
      const int coln = wn * 64 + j * 16 + (lane & 15);
      const float bv = bias1[coln];
#pragma unroll
      for (int i = 0; i < 4; ++i) {
        const int rown = wm * 64 + i * 16 + ((lane >> 4) << 2);
#pragma unroll
        for (int r = 0; r < 4; ++r)
          pt[(rown + r) * 136 + coln] = f2b(tanhfast(acc[i][j][r] + bv));
      }
    }
    __syncthreads();
    short8v wfr[4];
#pragma unroll
    for (int ks = 0; ks < 4; ++ks) {
      short8v f = {0, 0, 0, 0, 0, 0, 0, 0};
      if (lrow < 8) {
        const float* src = Wa2 + lrow * 128 + ks * 32 + lk8;
        const float4 a = *reinterpret_cast<const float4*>(src);
        const float4 b = *reinterpret_cast<const float4*>(src + 4);
        f[0] = (short)f2b(a.x); f[1] = (short)f2b(a.y);
        f[2] = (short)f2b(a.z); f[3] = (short)f2b(a.w);
        f[4] = (short)f2b(b.x); f[5] = (short)f2b(b.y);
        f[6] = (short)f2b(b.z); f[7] = (short)f2b(b.w);
      }
      wfr[ks] = f;
    }
    float* pot = reinterpret_cast<float*>(C);
#pragma unroll
    for (int ff = 0; ff < 2; ++ff) {
      const int fr = wave * 2 + ff;
      f32x4 pacc = {0.f, 0.f, 0.f, 0.f};
#pragma unroll
      for (int ks = 0; ks < 4; ++ks) {
        const short8v af = *reinterpret_cast<const short8v*>(
            &pt[(fr * 16 + lrow) * 136 + ks * 32 + lk8]);
        pacc = __builtin_amdgcn_mfma_f32_16x16x32_bf16(af, wfr[ks], pacc, 0, 0, 0);
      }
      if ((lane & 15) < 8) {
#pragma unroll
        for (int r = 0; r < 4; ++r)
          pot[(size_t)(m0 + fr * 16 + ((lane >> 4) << 2) + r) * 8 + (lane & 15)] = pacc[r];
      }
    }
  } else {
#pragma unroll
    for (int j = 0; j < 4; ++j) {
      const int gn = n0 + wn * 64 + j * 16 + (lane & 15);
      float bv = bias1[gn];
      if (bias2) bv += bias2[gn];
#pragma unroll
      for (int i = 0; i < 4; ++i) {
        const int gmb = m0 + wm * 64 + i * 16 + ((lane >> 4) << 2);
#pragma unroll
        for (int r = 0; r < 4; ++r) {
          const float v = acc[i][j][r] + bv;
          const size_t oidx = (size_t)(gmb + r) * N + gn;
          if constexpr (sizeof(CT) == 2) C[oidx] = f2b(v); else C[oidx] = v;
        }
      }
    }
  }
}

// MFMA bidirectional chunked LSTM (round-11 structure, best measured: 304us).
// 256 blocks (dir=bid>>7, batch pair), 8 waves. Batch rows at A-rows 0,4 ->
// gates land in reg0 of lanes 0-31 (no cross-lane exchange). pgbuf 3-step
// prefetch; lgkm-only barrier (T4); + T5 setprio around the MFMA cluster.
__global__ __launch_bounds__(512, 2) void lstm_k(const unsigned short* __restrict__ P,
    const float* __restrict__ Whh, const float* __restrict__ wtime,
    unsigned short* __restrict__ Y) {
  const int tid = threadIdx.x;
  const int lane = tid & 63;
  const int w = tid >> 6;
  const int u = lane & 15;
  const int q = lane >> 4;
  const int dir = blockIdx.x >> 7;
  const int b0 = (blockIdx.x & 127) * 2;

  __shared__ unsigned short hbuf[2][2048];   // [buf][koct16][row16][8]; rows 0,4 live
  __shared__ unsigned int pgbuf[2][512];     // [buf][row*256 + word]
  __shared__ unsigned short histb[4096];     // [slot16][row2][col128]
  __shared__ float wts[32];

  short8v bfrag[4][4];
#pragma unroll
  for (int gt = 0; gt < 4; ++gt) {
    const int col = gt * 128 + w * 16 + u;
#pragma unroll
    for (int ks = 0; ks < 4; ++ks) {
      const int k0 = ks * 32 + q * 8;
      const float4 w0 = *reinterpret_cast<const float4*>(Whh + (size_t)col * 128 + k0);
      const float4 w1 = *reinterpret_cast<const float4*>(Whh + (size_t)col * 128 + k0 + 4);
      short8v f;
      f[0] = (short)f2b(w0.x); f[1] = (short)f2b(w0.y);
      f[2] = (short)f2b(w0.z); f[3] = (short)f2b(w0.w);
      f[4] = (short)f2b(w1.x); f[5] = (short)f2b(w1.y);
      f[6] = (short)f2b(w1.z); f[7] = (short)f2b(w1.w);
      bfrag[gt][ks] = f;
    }
  }

  for (int i = tid; i < 2048; i += 512) { hbuf[0][i] = 0; hbuf[1][i] = 0; }
  if (tid < 32) wts[tid] = wtime[tid];
  const unsigned int* P32 = reinterpret_cast<const unsigned int*>(P);
  const int prow = tid >> 8, pword = tid & 255;
  const size_t pthread = (size_t)(b0 + prow) * 256 + pword;
  const ptrdiff_t dstep = (dir ? -(ptrdiff_t)1 : (ptrdiff_t)1) * (ptrdiff_t)(Bb * 256);
  unsigned int np_h1 = 0, np_h2 = 0;
  {
    const int t0 = dir ? (Tt - 1) : 0;
    pgbuf[0][tid] = P32[(size_t)t0 * Bb * 256 + pthread];
    const int t1 = dir ? (Tt - 2) : 1;
    np_h1 = P32[(size_t)t1 * Bb * 256 + pthread];
    const int t2 = dir ? (Tt - 3) : 2;
    np_h2 = P32[(size_t)t2 * Bb * 256 + pthread];
  }
  ptrdiff_t poff = (ptrdiff_t)((size_t)(dir ? (Tt - 4) : 3) * Bb * 256 + pthread);
  const int r_own = q & 1;
  const int colh = w * 16 + u;
  float c_st = 0.f, ha = 0.f, ca = 0.f;
  __syncthreads();

  auto body = [&](int s, int cur) {
    unsigned int np_new = 0;
    if (s < Tt - 3) np_new = P32[poff];
    short8v afrag[4];
#pragma unroll
    for (int ks = 0; ks < 4; ++ks)
      afrag[ks] = *reinterpret_cast<const short8v*>(&hbuf[cur][(ks * 4 + q) * 128 + u * 8]);
    __builtin_amdgcn_s_setprio(1);           // T5: favor MFMA-issuing wave
    f32x4 gacc[4];
#pragma unroll
    for (int gt = 0; gt < 4; ++gt) {
      f32x4 acc = {0.f, 0.f, 0.f, 0.f};
#pragma unroll
      for (int ks = 0; ks < 4; ++ks)
        acc = __builtin_amdgcn_mfma_f32_16x16x32_bf16(afrag[ks], bfrag[gt][ks], acc, 0, 0, 0);
      gacc[gt] = acc;
    }
    __builtin_amdgcn_s_setprio(0);
    if (s + 1 < Tt) pgbuf[cur ^ 1][tid] = np_h1;
    if (lane < 32) {
      const float wt = wts[s & 31];
      float g4[4];
#pragma unroll
      for (int gt = 0; gt < 4; ++gt) {
        const unsigned int pw = pgbuf[cur][r_own * 256 + gt * 64 + (colh >> 1)];
        const unsigned short pb = (colh & 1) ? (unsigned short)(pw >> 16)
                                             : (unsigned short)(pw & 0xFFFF);
        g4[gt] = gacc[gt][0] + b2f(pb);
      }
      float cs = sigf(g4[1]) * c_st + sigf(g4[0]) * tanhfast(g4[2]);
      float hn = sigf(g4[3]) * tanhfast(cs);
      ha += wt * hn;
      ca += wt * cs;
      if ((s & 31) == 31) { hn = ha; cs = ca; ha = 0.f; ca = 0.f; }
      c_st = cs;
      const unsigned short hb = f2b(hn);
      hbuf[cur ^ 1][(colh >> 3) * 128 + r_own * 32 + (colh & 7)] = hb;
      histb[((s & 15) * 2 + r_own) * 128 + colh] = hb;
    }
    if ((s & 7) == 0 && s) {
      const int k = tid >> 6, r2 = (tid >> 5) & 1, c4 = (tid & 31) * 4;
      const int bs = s - 8;
      const uint2 v = *reinterpret_cast<const uint2*>(
          &histb[(((bs + k) & 15) * 2 + r2) * 128 + c4]);
      *reinterpret_cast<uint2*>(
          &Y[((size_t)(bs + k) * Bb + b0 + r2) * Dp + dir * Hh + c4]) = v;
    }
    block_sync_lds();
    np_h1 = np_h2;
    np_h2 = np_new;
    poff += dstep;
  };

  for (int s = 0; s < Tt; s += 2) {
    body(s, 0);
    body(s + 1, 1);
  }
  {
    const int k = tid >> 6, r2 = (tid >> 5) & 1, c4 = (tid & 31) * 4;
    const int bs = Tt - 8;
    const uint2 v = *reinterpret_cast<const uint2*>(
        &histb[(((bs + k) & 15) * 2 + r2) * 128 + c4]);
    *reinterpret_cast<uint2*>(
        &Y[((size_t)(bs + k) * Bb + b0 + r2) * Dp + dir * Hh + c4]) = v;
  }
}

// masked softmax over t for one (b,r); writes Wt[b][r][t]
__global__ __launch_bounds__(256) void softmax_k(const float* __restrict__ pot,
    const int* __restrict__ length, float* __restrict__ Wt) {
  const int b = blockIdx.x >> 3, r = blockIdx.x & 7;
  const int tid = threadIdx.x;
  const int len = length[b];
  __shared__ float rbuf[4];
  const int t1 = tid, t2 = tid + 256;
  const float x1 = (t1 < len) ? pot[((size_t)t1 * Bb + b) * 8 + r] : -INFINITY;
  const float x2 = (t2 < len) ? pot[((size_t)t2 * Bb + b) * 8 + r] : -INFINITY;
  float m = fmaxf(x1, x2);
#pragma unroll
  for (int off = 32; off >= 1; off >>= 1) m = fmaxf(m, __shfl_xor(m, off));
  if ((tid & 63) == 0) rbuf[tid >> 6] = m;
  __syncthreads();
  m = fmaxf(fmaxf(rbuf[0], rbuf[1]), fmaxf(rbuf[2], rbuf[3]));
  const float e1 = (t1 < len) ? __expf(x1 - m) : 0.f;
  const float e2 = (t2 < len) ? __expf(x2 - m) : 0.f;
  float ssum = e1 + e2;
#pragma unroll
  for (int off = 32; off >= 1; off >>= 1) ssum += __shfl_xor(ssum, off);
  __syncthreads();
  if ((tid & 63) == 0) rbuf[tid >> 6] = ssum;
  __syncthreads();
  ssum = rbuf[0] + rbuf[1] + rbuf[2] + rbuf[3];
  const float inv = 1.0f / ssum;
  float* wrow = Wt + ((size_t)b * 8 + r) * Tt;
  wrow[t1] = e1 * inv;
  wrow[t2] = e2 * inv;
}

// Per-b: pooled = sum_t w[r][t]*Y[t][b][:], logits, log_softmax, gram penalty.
__global__ __launch_bounds__(256) void pool_k(const unsigned short* __restrict__ Y,
    const float* __restrict__ Wt, const float* __restrict__ Wout,
    const float* __restrict__ bout, float* __restrict__ outF,
    float* __restrict__ penpart) {
  const int b = blockIdx.x;
  const int tid = threadIdx.x;
  __shared__ float ws[8 * 513];
  __shared__ float pooled[2048];
  __shared__ float red[256];
  __shared__ float lg[8];
  for (int i = tid; i < 4096; i += 256) ws[(i >> 9) * 513 + (i & 511)] = Wt[(size_t)b * 4096 + i];
  __syncthreads();
  float acc[8] = {};
  for (int t = 0; t < Tt; ++t) {
    const float y = b2f(Y[((size_t)t * Bb + b) * Dp + tid]);
#pragma unroll
    for (int r = 0; r < 8; ++r) acc[r] += ws[r * 513 + t] * y;
  }
#pragma unroll
  for (int r = 0; r < 8; ++r) pooled[r * 256 + tid] = acc[r];
  __syncthreads();
  for (int o = 0; o < 7; ++o) {
    float p = 0.f;
    for (int j = tid; j < 2048; j += 256) p += pooled[j] * Wout[(size_t)o * 2048 + j];
    red[tid] = p;
    __syncthreads();
    for (int st = 128; st >= 1; st >>= 1) {
      if (tid < st) red[tid] += red[tid + st];
      __syncthreads();
    }
    if (tid == 0) lg[o] = red[0] + bout[o];
    __syncthreads();
  }
  if (tid == 0) {
    float mx = lg[0];
    for (int o = 1; o < 7; ++o) mx = fmaxf(mx, lg[o]);
    float ssum = 0.f;
    for (int o = 0; o < 7; ++o) ssum += __expf(lg[o] - mx);
    const float lse = mx + __logf(ssum);
    for (int o = 0; o < 7; ++o) outF[b * 7 + o] = lg[o] - lse;
  }
  for (int i = tid; i < 4096; i += 256) {
    const int rr = i >> 9, t = i & 511;
    ws[rr * 513 + t] = sqrtf(ws[rr * 513 + t]);
  }
  __syncthreads();
  float pp = 0.f;
  if (tid < 64) {
    const int rr = tid >> 3, ssi = tid & 7;
    float g = 0.f;
    for (int t = 0; t < Tt; ++t) g += ws[rr * 513 + t] * ws[ssi * 513 + t];
    const float d = g - 1.0f;
    pp = d * d;
  }
  red[tid] = pp;
  __syncthreads();
  for (int st = 128; st >= 1; st >>= 1) {
    if (tid < st) red[tid] += red[tid + st];
    __syncthreads();
  }
  if (tid == 0) penpart[b] = red[0];
}

__global__ __launch_bounds__(256) void penred_k(const float* __restrict__ penpart,
                                                float* __restrict__ outp) {
  const int tid = threadIdx.x;
  __shared__ float red[256];
  red[tid] = penpart[tid];
  __syncthreads();
  for (int st = 128; st >= 1; st >>= 1) {
    if (tid < st) red[tid] += red[tid + st];
    __syncthreads();
  }
  if (tid == 0) outp[0] = red[0];
}

} // namespace

extern "C" void kernel_launch(void* const* d_in, const int* in_sizes, int n_in,
                              void* d_out, int out_size, void* d_ws, size_t ws_size,
                              hipStream_t stream) {
  (void)in_sizes; (void)n_in; (void)out_size;
  const float* x     = (const float*)d_in[0];
  const float* W_in  = (const float*)d_in[1];
  const float* b_in  = (const float*)d_in[2];
  const float* W_ih  = (const float*)d_in[3];
  const float* b_ih  = (const float*)d_in[4];
  const float* W_hh  = (const float*)d_in[5];
  const float* b_hh  = (const float*)d_in[6];
  const float* wtime = (const float*)d_in[7];
  const float* W_a1  = (const float*)d_in[8];
  const float* b_a1  = (const float*)d_in[9];
  const float* W_a2  = (const float*)d_in[10];
  const float* W_out = (const float*)d_in[11];
  const float* b_out = (const float*)d_in[12];
  const int*   length= (const int*)d_in[13];
  float* outF = (float*)d_out;

  typedef unsigned short bf16;
  char* ws = (char*)d_ws;
  size_t off = 0;
  auto alloc = [&](size_t bytes) {
    void* p = ws + off; off += (bytes + 255) & ~(size_t)255; return p;
  };
  bf16*  act  = (bf16*)alloc((size_t)M * 256 * 2);   // activations [T*B][256]
  bf16*  Pg   = (bf16*)alloc((size_t)M * 512 * 2);   // pre-gates  [T*B][512]
  bf16*  xb   = (bf16*)alloc((size_t)M * 128 * 2);   // x transposed+bf16
  float* pot  = (float*)alloc((size_t)M * 8 * 4);
  float* Wt   = (float*)alloc((size_t)Bb * 8 * Tt * 4);
  float* penp = (float*)alloc(Bb * 4);
  bf16*  Wihb = (bf16*)alloc(512 * 256 * 2);
  bf16*  Winb = (bf16*)alloc(256 * 128 * 2);
  bf16*  Wa1b = (bf16*)alloc(128 * 256 * 2);

  if (ws_size < off) return;  // workspace too small: clean absmax-fail, not a crash

  const dim3 blk(256);
  // pre-conversions (bit-identical to the stage-time conversions they replace)
  wconv_k<<<dim3(32),  blk, 0, stream>>>(W_in, Winb);
  wconv_k<<<dim3(128), blk, 0, stream>>>(W_ih, Wihb);
  wconv_k<<<dim3(32),  blk, 0, stream>>>(W_a1, Wa1b);
  xconv_k<<<dim3(M / 8), blk, 0, stream>>>(x, xb);
  // input layer
  mgemm_k<128, 0, bf16><<<dim3(2, M / 128), blk, 0, stream>>>(xb, Winb, b_in, nullptr, nullptr, act, 256);
  // layer 0
  mgemm_k<256, 0, bf16><<<dim3(4, M / 128), blk, 0, stream>>>(act, Wihb, b_ih, b_hh, nullptr, Pg, 512);
  lstm_k<<<dim3(256), dim3(512), 0, stream>>>(Pg, W_hh, wtime, act);
  // layer 1 (shared weights)
  mgemm_k<256, 0, bf16><<<dim3(4, M / 128), blk, 0, stream>>>(act, Wihb, b_ih, b_hh, nullptr, Pg, 512);
  lstm_k<<<dim3(256), dim3(512), 0, stream>>>(Pg, W_hh, wtime, act);
  // attention: tanh GEMM fused with pot projection
  mgemm_k<256, 1, float><<<dim3(1, M / 128), blk, 0, stream>>>(act, Wa1b, b_a1, nullptr, W_a2, pot, 128);
  softmax_k<<<dim3(Bb * 8), blk, 0, stream>>>(pot, length, Wt);
  pool_k<<<dim3(Bb), blk, 0, stream>>>(act, Wt, W_out, b_out, outF, penp);
  penred_k<<<dim3(1), blk, 0, stream>>>(penp, outF + Bb * 7);
}

// Round 17
// 888.998 us; speedup vs baseline: 1.5904x; 1.0114x over previous
//
#include <hip/hip_runtime.h>
#include <math.h>

namespace {

constexpr int Bb = 256, Tt = 512, Dp = 256, Hh = 128, G = 512;
constexpr int M = Tt * Bb; // 131072 rows (t-major: row = t*B + b)

typedef __attribute__((ext_vector_type(8))) short short8v;
typedef __attribute__((ext_vector_type(4))) float f32x4;

__device__ __forceinline__ float sigf(float x) {
  return __builtin_amdgcn_rcpf(1.0f + __expf(-x));
}
__device__ __forceinline__ float tanhfast(float x) {
  const float e = __expf(2.0f * x);
  return 1.0f - 2.0f * __builtin_amdgcn_rcpf(e + 1.0f);
}
__device__ __forceinline__ float b2f(unsigned short u) {
  return __uint_as_float((unsigned int)u << 16);
}
__device__ __forceinline__ unsigned short f2b(float f) {
  unsigned int u = __float_as_uint(f);
  u += 0x7FFFu + ((u >> 16) & 1u);   // round-to-nearest-even
  return (unsigned short)(u >> 16);
}
__device__ __forceinline__ unsigned int pack2(float a, float b) {
  return (unsigned int)f2b(a) | ((unsigned int)f2b(b) << 16);
}
// direct global->LDS DMA, 16B per lane (dest = wave-uniform base + lane*16)
__device__ __forceinline__ void gload16(const unsigned short* g, unsigned short* l) {
  __builtin_amdgcn_global_load_lds(
      (const __attribute__((address_space(1))) unsigned int*)g,
      (__attribute__((address_space(3))) unsigned int*)l, 16, 0, 0);
}
__device__ __forceinline__ void block_sync_lds() {
  __builtin_amdgcn_sched_barrier(0);
  asm volatile("s_waitcnt lgkmcnt(0)" ::: "memory");
  __builtin_amdgcn_s_barrier();
  __builtin_amdgcn_sched_barrier(0);
}

// fp32 -> bf16 flat convert (weights). n multiple of 1024.
__global__ __launch_bounds__(256) void wconv_k(const float* __restrict__ src,
                                               unsigned short* __restrict__ dst) {
  const int i = (blockIdx.x * 256 + threadIdx.x) * 4;
  const float4 v = *reinterpret_cast<const float4*>(src + i);
  uint2 o; o.x = pack2(v.x, v.y); o.y = pack2(v.z, v.w);
  *reinterpret_cast<uint2*>(dst + i) = o;
}

// x[B][T][128] fp32 -> xb[(t*256+b)][128] bf16
__global__ __launch_bounds__(256) void xconv_k(const float* __restrict__ x,
                                               unsigned short* __restrict__ out) {
  const int tid = threadIdx.x;
  const int m = blockIdx.x * 8 + (tid >> 5);
  const int t = m >> 8, b = m & 255;
  const int c4 = (tid & 31) * 4;
  const float4 v = *reinterpret_cast<const float4*>(x + ((size_t)b * Tt + t) * 128 + c4);
  uint2 o; o.x = pack2(v.x, v.y); o.y = pack2(v.z, v.w);
  *reinterpret_cast<uint2*>(out + (size_t)m * 128 + c4) = o;
}

// MFMA GEMM, all-bf16, global_load_lds staging (fragment-major chunks).
// 128x128 tile, 4 waves (64x64 each), BK=64 double-buffered.
// T1 XCD swizzle: contiguous work ranges per XCD -> A-tile re-reads hit L2.
// POT=1 (attention): tanh epilogue -> LDS tile -> MFMA vs Wa2 -> pot[M][8] f32.
template<int K, int POT, typename CT>
__global__ __launch_bounds__(256) void mgemm_k(const unsigned short* __restrict__ A,
    const unsigned short* __restrict__ W, const float* __restrict__ bias1,
    const float* __restrict__ bias2, const float* __restrict__ Wa2,
    CT* __restrict__ C, int N) {
  constexpr int NK = K / 64;
  __shared__ unsigned short smem[32768];   // aLds(2x8192) | wLds(2x8192); POT reuses as ptile
  unsigned short* aLds = smem;
  unsigned short* wLds = smem + 16384;
  const int tid = threadIdx.x;
  const int lane = tid & 63;
  const int wave = tid >> 6;
  const int wm = wave >> 1, wn = wave & 1;
  // XCD-aware swizzle (grids are multiples of 8 -> bijective):
  // hw block `lin` (xcd = lin%8) processes work item (lin%8)*cpx + lin/8,
  // so each XCD owns a CONTIGUOUS range; the nx n-tiles sharing an A-row-tile
  // are adjacent in that range -> A re-reads are XCD-L2 hits.
  const int nx = gridDim.x;
  const int nwg = nx * gridDim.y;
  const int lin = blockIdx.y * nx + blockIdx.x;
  const int swz = (lin & 7) * (nwg >> 3) + (lin >> 3);
  const int m0 = (swz / nx) * 128, n0 = (swz % nx) * 128;
  const int lrow = lane & 15, lk8 = (lane >> 4) * 8;

  const unsigned short* Ab = A + (size_t)(m0 + lrow) * K + lk8;
  const unsigned short* Wb = W + (size_t)(n0 + lrow) * K + lk8;

  auto stage = [&](int buf, int kb) {
#pragma unroll
    for (int i = 0; i < 4; ++i) {
      const int c = wave * 4 + i, f = c & 7, kc = c >> 3;
      const size_t go = (size_t)(f * 16) * K + kb * 64 + kc * 32;
      gload16(Ab + go, &aLds[buf * 8192 + c * 512]);
      gload16(Wb + go, &wLds[buf * 8192 + c * 512]);
    }
  };

  f32x4 acc[4][4] = {};
  stage(0, 0);
  __syncthreads();
  int cur = 0;
  for (int kb = 0; kb < NK; ++kb) {
    if (kb + 1 < NK) stage(cur ^ 1, kb + 1);   // issue next-tile DMA before compute
#pragma unroll
    for (int kc = 0; kc < 2; ++kc) {
      short8v af[4], bfr[4];
#pragma unroll
      for (int i = 0; i < 4; ++i)
        af[i] = *reinterpret_cast<const short8v*>(
            &aLds[cur * 8192 + ((kc * 8 + wm * 4 + i) * 64 + lane) * 8]);
#pragma unroll
      for (int j = 0; j < 4; ++j)
        bfr[j] = *reinterpret_cast<const short8v*>(
            &wLds[cur * 8192 + ((kc * 8 + wn * 4 + j) * 64 + lane) * 8]);
#pragma unroll
      for (int i = 0; i < 4; ++i)
#pragma unroll
        for (int j = 0; j < 4; ++j)
          acc[i][j] = __builtin_amdgcn_mfma_f32_16x16x32_bf16(af[i], bfr[j], acc[i][j], 0, 0, 0);
    }
    __syncthreads();   // drains staged DMA (vmcnt) + LDS reads; buffer swap safe
    cur ^= 1;
  }

  if constexpr (POT) {
    unsigned short* pt = smem;
#pragma unroll
    for (int j = 0; j < 4; ++j) {
      const int coln = wn * 64 + j * 16 + (lane & 15);
      const float bv = bias1[coln];
#pragma unroll
      for (int i = 0; i < 4; ++i) {
        const int rown = wm * 64 + i * 16 + ((lane >> 4) << 2);
#pragma unroll
        for (int r = 0; r < 4; ++r)
          pt[(rown + r) * 136 + coln] = f2b(tanhfast(acc[i][j][r] + bv));
      }
    }
    __syncthreads();
    short8v wfr[4];
#pragma unroll
    for (int ks = 0; ks < 4; ++ks) {
      short8v f = {0, 0, 0, 0, 0, 0, 0, 0};
      if (lrow < 8) {
        const float* src = Wa2 + lrow * 128 + ks * 32 + lk8;
        const float4 a = *reinterpret_cast<const float4*>(src);
        const float4 b = *reinterpret_cast<const float4*>(src + 4);
        f[0] = (short)f2b(a.x); f[1] = (short)f2b(a.y);
        f[2] = (short)f2b(a.z); f[3] = (short)f2b(a.w);
        f[4] = (short)f2b(b.x); f[5] = (short)f2b(b.y);
        f[6] = (short)f2b(b.z); f[7] = (short)f2b(b.w);
      }
      wfr[ks] = f;
    }
    float* pot = reinterpret_cast<float*>(C);
#pragma unroll
    for (int ff = 0; ff < 2; ++ff) {
      const int fr = wave * 2 + ff;
      f32x4 pacc = {0.f, 0.f, 0.f, 0.f};
#pragma unroll
      for (int ks = 0; ks < 4; ++ks) {
        const short8v af = *reinterpret_cast<const short8v*>(
            &pt[(fr * 16 + lrow) * 136 + ks * 32 + lk8]);
        pacc = __builtin_amdgcn_mfma_f32_16x16x32_bf16(af, wfr[ks], pacc, 0, 0, 0);
      }
      if ((lane & 15) < 8) {
#pragma unroll
        for (int r = 0; r < 4; ++r)
          pot[(size_t)(m0 + fr * 16 + ((lane >> 4) << 2) + r) * 8 + (lane & 15)] = pacc[r];
      }
    }
  } else {
#pragma unroll
    for (int j = 0; j < 4; ++j) {
      const int gn = n0 + wn * 64 + j * 16 + (lane & 15);
      float bv = bias1[gn];
      if (bias2) bv += bias2[gn];
#pragma unroll
      for (int i = 0; i < 4; ++i) {
        const int gmb = m0 + wm * 64 + i * 16 + ((lane >> 4) << 2);
#pragma unroll
        for (int r = 0; r < 4; ++r) {
          const float v = acc[i][j][r] + bv;
          const size_t oidx = (size_t)(gmb + r) * N + gn;
          if constexpr (sizeof(CT) == 2) C[oidx] = f2b(v); else C[oidx] = v;
        }
      }
    }
  }
}

// MFMA bidirectional chunked LSTM (round-11 structure, best measured: 304us).
__global__ __launch_bounds__(512, 2) void lstm_k(const unsigned short* __restrict__ P,
    const float* __restrict__ Whh, const float* __restrict__ wtime,
    unsigned short* __restrict__ Y) {
  const int tid = threadIdx.x;
  const int lane = tid & 63;
  const int w = tid >> 6;
  const int u = lane & 15;
  const int q = lane >> 4;
  const int dir = blockIdx.x >> 7;
  const int b0 = (blockIdx.x & 127) * 2;

  __shared__ unsigned short hbuf[2][2048];   // [buf][koct16][row16][8]; rows 0,4 live
  __shared__ unsigned int pgbuf[2][512];     // [buf][row*256 + word]
  __shared__ unsigned short histb[4096];     // [slot16][row2][col128]
  __shared__ float wts[32];

  short8v bfrag[4][4];
#pragma unroll
  for (int gt = 0; gt < 4; ++gt) {
    const int col = gt * 128 + w * 16 + u;
#pragma unroll
    for (int ks = 0; ks < 4; ++ks) {
      const int k0 = ks * 32 + q * 8;
      const float4 w0 = *reinterpret_cast<const float4*>(Whh + (size_t)col * 128 + k0);
      const float4 w1 = *reinterpret_cast<const float4*>(Whh + (size_t)col * 128 + k0 + 4);
      short8v f;
      f[0] = (short)f2b(w0.x); f[1] = (short)f2b(w0.y);
      f[2] = (short)f2b(w0.z); f[3] = (short)f2b(w0.w);
      f[4] = (short)f2b(w1.x); f[5] = (short)f2b(w1.y);
      f[6] = (short)f2b(w1.z); f[7] = (short)f2b(w1.w);
      bfrag[gt][ks] = f;
    }
  }

  for (int i = tid; i < 2048; i += 512) { hbuf[0][i] = 0; hbuf[1][i] = 0; }
  if (tid < 32) wts[tid] = wtime[tid];
  const unsigned int* P32 = reinterpret_cast<const unsigned int*>(P);
  const int prow = tid >> 8, pword = tid & 255;
  const size_t pthread = (size_t)(b0 + prow) * 256 + pword;
  const ptrdiff_t dstep = (dir ? -(ptrdiff_t)1 : (ptrdiff_t)1) * (ptrdiff_t)(Bb * 256);
  unsigned int np_h1 = 0, np_h2 = 0;
  {
    const int t0 = dir ? (Tt - 1) : 0;
    pgbuf[0][tid] = P32[(size_t)t0 * Bb * 256 + pthread];
    const int t1 = dir ? (Tt - 2) : 1;
    np_h1 = P32[(size_t)t1 * Bb * 256 + pthread];
    const int t2 = dir ? (Tt - 3) : 2;
    np_h2 = P32[(size_t)t2 * Bb * 256 + pthread];
  }
  ptrdiff_t poff = (ptrdiff_t)((size_t)(dir ? (Tt - 4) : 3) * Bb * 256 + pthread);
  const int r_own = q & 1;
  const int colh = w * 16 + u;
  float c_st = 0.f, ha = 0.f, ca = 0.f;
  __syncthreads();

  auto body = [&](int s, int cur) {
    unsigned int np_new = 0;
    if (s < Tt - 3) np_new = P32[poff];
    short8v afrag[4];
#pragma unroll
    for (int ks = 0; ks < 4; ++ks)
      afrag[ks] = *reinterpret_cast<const short8v*>(&hbuf[cur][(ks * 4 + q) * 128 + u * 8]);
    f32x4 gacc[4];
#pragma unroll
    for (int gt = 0; gt < 4; ++gt) {
      f32x4 acc = {0.f, 0.f, 0.f, 0.f};
#pragma unroll
      for (int ks = 0; ks < 4; ++ks)
        acc = __builtin_amdgcn_mfma_f32_16x16x32_bf16(afrag[ks], bfrag[gt][ks], acc, 0, 0, 0);
      gacc[gt] = acc;
    }
    if (s + 1 < Tt) pgbuf[cur ^ 1][tid] = np_h1;
    if (lane < 32) {
      const float wt = wts[s & 31];
      float g4[4];
#pragma unroll
      for (int gt = 0; gt < 4; ++gt) {
        const unsigned int pw = pgbuf[cur][r_own * 256 + gt * 64 + (colh >> 1)];
        const unsigned short pb = (colh & 1) ? (unsigned short)(pw >> 16)
                                             : (unsigned short)(pw & 0xFFFF);
        g4[gt] = gacc[gt][0] + b2f(pb);
      }
      float cs = sigf(g4[1]) * c_st + sigf(g4[0]) * tanhfast(g4[2]);
      float hn = sigf(g4[3]) * tanhfast(cs);
      ha += wt * hn;
      ca += wt * cs;
      if ((s & 31) == 31) { hn = ha; cs = ca; ha = 0.f; ca = 0.f; }
      c_st = cs;
      const unsigned short hb = f2b(hn);
      hbuf[cur ^ 1][(colh >> 3) * 128 + r_own * 32 + (colh & 7)] = hb;
      histb[((s & 15) * 2 + r_own) * 128 + colh] = hb;
    }
    if ((s & 7) == 0 && s) {
      const int k = tid >> 6, r2 = (tid >> 5) & 1, c4 = (tid & 31) * 4;
      const int bs = s - 8;
      const uint2 v = *reinterpret_cast<const uint2*>(
          &histb[(((bs + k) & 15) * 2 + r2) * 128 + c4]);
      *reinterpret_cast<uint2*>(
          &Y[((size_t)(bs + k) * Bb + b0 + r2) * Dp + dir * Hh + c4]) = v;
    }
    block_sync_lds();
    np_h1 = np_h2;
    np_h2 = np_new;
    poff += dstep;
  };

  for (int s = 0; s < Tt; s += 2) {
    body(s, 0);
    body(s + 1, 1);
  }
  {
    const int k = tid >> 6, r2 = (tid >> 5) & 1, c4 = (tid & 31) * 4;
    const int bs = Tt - 8;
    const uint2 v = *reinterpret_cast<const uint2*>(
        &histb[(((bs + k) & 15) * 2 + r2) * 128 + c4]);
    *reinterpret_cast<uint2*>(
        &Y[((size_t)(bs + k) * Bb + b0 + r2) * Dp + dir * Hh + c4]) = v;
  }
}

// masked softmax over t for one (b,r); writes Wt[b][r][t]
__global__ __launch_bounds__(256) void softmax_k(const float* __restrict__ pot,
    const int* __restrict__ length, float* __restrict__ Wt) {
  const int b = blockIdx.x >> 3, r = blockIdx.x & 7;
  const int tid = threadIdx.x;
  const int len = length[b];
  __shared__ float rbuf[4];
  const int t1 = tid, t2 = tid + 256;
  const float x1 = (t1 < len) ? pot[((size_t)t1 * Bb + b) * 8 + r] : -INFINITY;
  const float x2 = (t2 < len) ? pot[((size_t)t2 * Bb + b) * 8 + r] : -INFINITY;
  float m = fmaxf(x1, x2);
#pragma unroll
  for (int off = 32; off >= 1; off >>= 1) m = fmaxf(m, __shfl_xor(m, off));
  if ((tid & 63) == 0) rbuf[tid >> 6] = m;
  __syncthreads();
  m = fmaxf(fmaxf(rbuf[0], rbuf[1]), fmaxf(rbuf[2], rbuf[3]));
  const float e1 = (t1 < len) ? __expf(x1 - m) : 0.f;
  const float e2 = (t2 < len) ? __expf(x2 - m) : 0.f;
  float ssum = e1 + e2;
#pragma unroll
  for (int off = 32; off >= 1; off >>= 1) ssum += __shfl_xor(ssum, off);
  __syncthreads();
  if ((tid & 63) == 0) rbuf[tid >> 6] = ssum;
  __syncthreads();
  ssum = rbuf[0] + rbuf[1] + rbuf[2] + rbuf[3];
  const float inv = 1.0f / ssum;
  float* wrow = Wt + ((size_t)b * 8 + r) * Tt;
  wrow[t1] = e1 * inv;
  wrow[t2] = e2 * inv;
}

// Per-b: pooled = sum_t w[r][t]*Y[t][b][:], logits, log_softmax, gram penalty.
__global__ __launch_bounds__(256) void pool_k(const unsigned short* __restrict__ Y,
    const float* __restrict__ Wt, const float* __restrict__ Wout,
    const float* __restrict__ bout, float* __restrict__ outF,
    float* __restrict__ penpart) {
  const int b = blockIdx.x;
  const int tid = threadIdx.x;
  __shared__ float ws[8 * 513];
  __shared__ float pooled[2048];
  __shared__ float red[256];
  __shared__ float lg[8];
  for (int i = tid; i < 4096; i += 256) ws[(i >> 9) * 513 + (i & 511)] = Wt[(size_t)b * 4096 + i];
  __syncthreads();
  float acc[8] = {};
  for (int t = 0; t < Tt; ++t) {
    const float y = b2f(Y[((size_t)t * Bb + b) * Dp + tid]);
#pragma unroll
    for (int r = 0; r < 8; ++r) acc[r] += ws[r * 513 + t] * y;
  }
#pragma unroll
  for (int r = 0; r < 8; ++r) pooled[r * 256 + tid] = acc[r];
  __syncthreads();
  for (int o = 0; o < 7; ++o) {
    float p = 0.f;
    for (int j = tid; j < 2048; j += 256) p += pooled[j] * Wout[(size_t)o * 2048 + j];
    red[tid] = p;
    __syncthreads();
    for (int st = 128; st >= 1; st >>= 1) {
      if (tid < st) red[tid] += red[tid + st];
      __syncthreads();
    }
    if (tid == 0) lg[o] = red[0] + bout[o];
    __syncthreads();
  }
  if (tid == 0) {
    float mx = lg[0];
    for (int o = 1; o < 7; ++o) mx = fmaxf(mx, lg[o]);
    float ssum = 0.f;
    for (int o = 0; o < 7; ++o) ssum += __expf(lg[o] - mx);
    const float lse = mx + __logf(ssum);
    for (int o = 0; o < 7; ++o) outF[b * 7 + o] = lg[o] - lse;
  }
  for (int i = tid; i < 4096; i += 256) {
    const int rr = i >> 9, t = i & 511;
    ws[rr * 513 + t] = sqrtf(ws[rr * 513 + t]);
  }
  __syncthreads();
  float pp = 0.f;
  if (tid < 64) {
    const int rr = tid >> 3, ssi = tid & 7;
    float g = 0.f;
    for (int t = 0; t < Tt; ++t) g += ws[rr * 513 + t] * ws[ssi * 513 + t];
    const float d = g - 1.0f;
    pp = d * d;
  }
  red[tid] = pp;
  __syncthreads();
  for (int st = 128; st >= 1; st >>= 1) {
    if (tid < st) red[tid] += red[tid + st];
    __syncthreads();
  }
  if (tid == 0) penpart[b] = red[0];
}

__global__ __launch_bounds__(256) void penred_k(const float* __restrict__ penpart,
                                                float* __restrict__ outp) {
  const int tid = threadIdx.x;
  __shared__ float red[256];
  red[tid] = penpart[tid];
  __syncthreads();
  for (int st = 128; st >= 1; st >>= 1) {
    if (tid < st) red[tid] += red[tid + st];
    __syncthreads();
  }
  if (tid == 0) outp[0] = red[0];
}

} // namespace

extern "C" void kernel_launch(void* const* d_in, const int* in_sizes, int n_in,
                              void* d_out, int out_size, void* d_ws, size_t ws_size,
                              hipStream_t stream) {
  (void)in_sizes; (void)n_in; (void)out_size;
  const float* x     = (const float*)d_in[0];
  const float* W_in  = (const float*)d_in[1];
  const float* b_in  = (const float*)d_in[2];
  const float* W_ih  = (const float*)d_in[3];
  const float* b_ih  = (const float*)d_in[4];
  const float* W_hh  = (const float*)d_in[5];
  const float* b_hh  = (const float*)d_in[6];
  const float* wtime = (const float*)d_in[7];
  const float* W_a1  = (const float*)d_in[8];
  const float* b_a1  = (const float*)d_in[9];
  const float* W_a2  = (const float*)d_in[10];
  const float* W_out = (const float*)d_in[11];
  const float* b_out = (const float*)d_in[12];
  const int*   length= (const int*)d_in[13];
  float* outF = (float*)d_out;

  typedef unsigned short bf16;
  char* ws = (char*)d_ws;
  size_t off = 0;
  auto alloc = [&](size_t bytes) {
    void* p = ws + off; off += (bytes + 255) & ~(size_t)255; return p;
  };
  bf16*  act  = (bf16*)alloc((size_t)M * 256 * 2);   // activations [T*B][256]
  bf16*  Pg   = (bf16*)alloc((size_t)M * 512 * 2);   // pre-gates  [T*B][512]
  bf16*  xb   = (bf16*)alloc((size_t)M * 128 * 2);   // x transposed+bf16
  float* pot  = (float*)alloc((size_t)M * 8 * 4);
  float* Wt   = (float*)alloc((size_t)Bb * 8 * Tt * 4);
  float* penp = (float*)alloc(Bb * 4);
  bf16*  Wihb = (bf16*)alloc(512 * 256 * 2);
  bf16*  Winb = (bf16*)alloc(256 * 128 * 2);
  bf16*  Wa1b = (bf16*)alloc(128 * 256 * 2);

  if (ws_size < off) return;  // workspace too small: clean absmax-fail, not a crash

  const dim3 blk(256);
  // pre-conversions (bit-identical to the stage-time conversions they replace)
  wconv_k<<<dim3(32),  blk, 0, stream>>>(W_in, Winb);
  wconv_k<<<dim3(128), blk, 0, stream>>>(W_ih, Wihb);
  wconv_k<<<dim3(32),  blk, 0, stream>>>(W_a1, Wa1b);
  xconv_k<<<dim3(M / 8), blk, 0, stream>>>(x, xb);
  // input layer
  mgemm_k<128, 0, bf16><<<dim3(2, M / 128), blk, 0, stream>>>(xb, Winb, b_in, nullptr, nullptr, act, 256);
  // layer 0
  mgemm_k<256, 0, bf16><<<dim3(4, M / 128), blk, 0, stream>>>(act, Wihb, b_ih, b_hh, nullptr, Pg, 512);
  lstm_k<<<dim3(256), dim3(512), 0, stream>>>(Pg, W_hh, wtime, act);
  // layer 1 (shared weights)
  mgemm_k<256, 0, bf16><<<dim3(4, M / 128), blk, 0, stream>>>(act, Wihb, b_ih, b_hh, nullptr, Pg, 512);
  lstm_k<<<dim3(256), dim3(512), 0, stream>>>(Pg, W_hh, wtime, act);
  // attention: tanh GEMM fused with pot projection
  mgemm_k<256, 1, float><<<dim3(1, M / 128), blk, 0, stream>>>(act, Wa1b, b_a1, nullptr, W_a2, pot, 128);
  softmax_k<<<dim3(Bb * 8), blk, 0, stream>>>(pot, length, Wt);
  pool_k<<<dim3(Bb), blk, 0, stream>>>(act, Wt, W_out, b_out, outF, penp);
  penred_k<<<dim3(1), blk, 0, stream>>>(penp, outF + Bb * 7);
}